// Round 14
// baseline (703.471 us; speedup 1.0000x reference)
//
#include <hip/hip_runtime.h>
#include <hip/hip_bf16.h>

#define NN 49152
#define GG 1024
#define EE 65536
#define ETOT 196608
#define FF 384
#define NEG_SLOPE 0.2f

typedef __attribute__((ext_vector_type(8))) short bf16x8;
typedef __attribute__((ext_vector_type(4))) float f32x4;

__device__ __forceinline__ float wave_sum(float v) {
#pragma unroll
    for (int m = 32; m; m >>= 1) v += __shfl_xor(v, m);
    return v;
}
__device__ __forceinline__ unsigned short f2bf(float f) {
    __hip_bfloat16 b = __float2bfloat16(f);
    return *reinterpret_cast<unsigned short*>(&b);
}
__device__ __forceinline__ float bflo(unsigned u) { return __uint_as_float(u << 16); }
__device__ __forceinline__ float bfhi(unsigned u) { return __uint_as_float(u & 0xffff0000u); }
__device__ __forceinline__ unsigned pk2(float lo, float hi) {
    return ((unsigned)f2bf(hi) << 16) | (unsigned)f2bf(lo);
}

__device__ __forceinline__ void gload_lds16(const void* g, void* l) {
    __builtin_amdgcn_global_load_lds(
        (const __attribute__((address_space(1))) unsigned int*)g,
        (__attribute__((address_space(3))) unsigned int*)l, 16, 0, 0);
}

__device__ __forceinline__ int swz(int row, int c16) {
    return row * 64 + ((c16 ^ ((row >> 1) & 3)) << 4);
}

// ================= generic MFMA bf16 GEMM (encoder / classifier) =================
template <int ACT, bool ABF, bool OBF>
__global__ __launch_bounds__(256) void gemm_mfma(
    const void* __restrict__ Ag, int K,
    const unsigned short* __restrict__ Btg,
    const float* __restrict__ bias,
    void* __restrict__ Cg, int ldc)
{
    __shared__ __align__(16) char As[8192];
    __shared__ __align__(16) char Bs[8192];
    const unsigned short* Bt = Btg;
    int t = threadIdx.x;
    int bm = blockIdx.x << 7, bn = blockIdx.y << 7;
    int lane = t & 63, wid = t >> 6, wr = wid >> 1, wc = wid & 1;
    f32x4 acc[4][4] = {};
    int ktn = K >> 5;
    for (int kt = 0; kt < ktn; ++kt) {
        int k0 = kt << 5;
#pragma unroll
        for (int ii = 0; ii < 2; ++ii) {
            int id = t + (ii << 8);
            int row = id >> 2, c = id & 3;
            int csrc = c ^ ((row >> 1) & 3);
            size_t ldsoff = (size_t)((wid << 10) + (ii << 12));
            if (ABF) {
                const unsigned short* srcA = (const unsigned short*)Ag + (size_t)(bm + row) * K + k0 + csrc * 8;
                gload_lds16(srcA, As + ldsoff);
            } else {
                const float* srcA = (const float*)Ag + (size_t)(bm + row) * K + k0 + c * 8;
                float4 a0 = *(const float4*)srcA;
                float4 a1 = *(const float4*)(srcA + 4);
                union { unsigned short u[8]; int4 v; } P;
                P.u[0] = f2bf(a0.x); P.u[1] = f2bf(a0.y); P.u[2] = f2bf(a0.z); P.u[3] = f2bf(a0.w);
                P.u[4] = f2bf(a1.x); P.u[5] = f2bf(a1.y); P.u[6] = f2bf(a1.z); P.u[7] = f2bf(a1.w);
                *(int4*)(As + swz(row, c)) = P.v;
            }
            const unsigned short* srcB = Bt + (size_t)(bn + row) * K + k0 + csrc * 8;
            gload_lds16(srcB, Bs + ldsoff);
        }
        __syncthreads();
        int c16 = lane >> 4;
        bf16x8 af[4], bfr[4];
#pragma unroll
        for (int m = 0; m < 4; ++m)
            af[m] = *(const bf16x8*)(As + swz((wr << 6) + (m << 4) + (lane & 15), c16));
#pragma unroll
        for (int n = 0; n < 4; ++n)
            bfr[n] = *(const bf16x8*)(Bs + swz((wc << 6) + (n << 4) + (lane & 15), c16));
#pragma unroll
        for (int m = 0; m < 4; ++m)
#pragma unroll
            for (int n = 0; n < 4; ++n)
                acc[m][n] = __builtin_amdgcn_mfma_f32_16x16x32_bf16(af[m], bfr[n], acc[m][n], 0, 0, 0);
        __syncthreads();
    }
#pragma unroll
    for (int m = 0; m < 4; ++m) {
#pragma unroll
        for (int n = 0; n < 4; ++n) {
            int row0 = bm + (wr << 6) + (m << 4) + ((lane >> 4) << 2);
            int col = bn + (wc << 6) + (n << 4) + (lane & 15);
            float bv = bias ? bias[col] : 0.f;
#pragma unroll
            for (int j = 0; j < 4; ++j) {
                float v = acc[m][n][j] + bv;
                if (ACT == 1) v = fmaxf(v, 0.f);
                if (OBF) ((unsigned short*)Cg)[(size_t)(row0 + j) * ldc + col] = f2bf(v);
                else     ((float*)Cg)[(size_t)(row0 + j) * ldc + col] = v;
            }
        }
    }
}

// ================= fused relation+qk GEMM: [NN,384] @ wcat[1280,384]^T =================
// Grid (10, 384): x = N-tile, y = M-tile -> the 10 blocks sharing an A-tile are
// dispatch-adjacent (A read ~once via L3); B (983 KB) stays hot in each L2.
// N-tiles 0-8 -> xt[r][node][f] (bf16); tile 9 cols 0-47 -> qkbuf (f32), rest pad.
__global__ __launch_bounds__(256) void gemm_rel(
    const unsigned short* __restrict__ hb,
    const unsigned short* __restrict__ wcat,
    unsigned short* __restrict__ xt,
    float* __restrict__ qkbuf)
{
    __shared__ __align__(16) char As[8192];
    __shared__ __align__(16) char Bs[8192];
    int t = threadIdx.x;
    int bm = blockIdx.y << 7, bn = blockIdx.x << 7;
    int lane = t & 63, wid = t >> 6, wr = wid >> 1, wc = wid & 1;
    f32x4 acc[4][4] = {};
    for (int kt = 0; kt < 12; ++kt) {
        int k0 = kt << 5;
#pragma unroll
        for (int ii = 0; ii < 2; ++ii) {
            int id = t + (ii << 8);
            int row = id >> 2, c = id & 3;
            int csrc = c ^ ((row >> 1) & 3);
            size_t ldsoff = (size_t)((wid << 10) + (ii << 12));
            const unsigned short* srcA = hb + (size_t)(bm + row) * FF + k0 + csrc * 8;
            gload_lds16(srcA, As + ldsoff);
            const unsigned short* srcB = wcat + (size_t)(bn + row) * FF + k0 + csrc * 8;
            gload_lds16(srcB, Bs + ldsoff);
        }
        __syncthreads();
        int c16 = lane >> 4;
        bf16x8 af[4], bfr[4];
#pragma unroll
        for (int m = 0; m < 4; ++m)
            af[m] = *(const bf16x8*)(As + swz((wr << 6) + (m << 4) + (lane & 15), c16));
#pragma unroll
        for (int n = 0; n < 4; ++n)
            bfr[n] = *(const bf16x8*)(Bs + swz((wc << 6) + (n << 4) + (lane & 15), c16));
#pragma unroll
        for (int m = 0; m < 4; ++m)
#pragma unroll
            for (int n = 0; n < 4; ++n)
                acc[m][n] = __builtin_amdgcn_mfma_f32_16x16x32_bf16(af[m], bfr[n], acc[m][n], 0, 0, 0);
        __syncthreads();
    }
    bool isqk = (bn >= 1152);
    int r = bn / FF;                 // valid when !isqk (no tile straddles a relation)
    int fbase = bn - r * FF;
#pragma unroll
    for (int m = 0; m < 4; ++m) {
#pragma unroll
        for (int n = 0; n < 4; ++n) {
            int row0 = bm + (wr << 6) + (m << 4) + ((lane >> 4) << 2);
            int cl = (wc << 6) + (n << 4) + (lane & 15);   // 0..127 within tile
#pragma unroll
            for (int j = 0; j < 4; ++j) {
                float v = acc[m][n][j];
                if (!isqk) {
                    xt[((size_t)r * NN + row0 + j) * FF + fbase + cl] = f2bf(v);
                } else if (cl < 48) {
                    qkbuf[(size_t)(row0 + j) * 48 + cl] = v;
                }
            }
        }
    }
}

// ================= f32-input fallback GEMM (small K / small N), optional bf16 out =================
template <int ACT, bool OBF>
__global__ __launch_bounds__(256) void gemm_k(
    const float* __restrict__ A, int K,
    const float* __restrict__ W, int Jw,
    const float* __restrict__ bias,
    void* __restrict__ Cg, int ldc, int jmax)
{
    __shared__ float Ash[16][64];
    __shared__ float Bsh[16][68];
    int tid = threadIdx.x;
    int bj = blockIdx.x << 6;
    int bm = blockIdx.y << 6;
    int tx = tid & 15, ty = tid >> 4;
    float acc[4][4] = {};
    int ktn = (K + 15) >> 4;
    int ar = tid >> 2;
    int aks = (tid & 3) << 2;
    int wk = tid >> 4;
    int wjs = (tid & 15) << 2;
    for (int kt = 0; kt < ktn; ++kt) {
        int k0 = kt << 4;
        const float* Ap = A + (size_t)(bm + ar) * K + k0 + aks;
#pragma unroll
        for (int i = 0; i < 4; ++i) {
            int k = k0 + aks + i;
            Ash[aks + i][ar] = (k < K) ? Ap[i] : 0.f;
        }
        const float* Wp = W + (size_t)(k0 + wk) * Jw + bj + wjs;
        bool kok = (k0 + wk) < K;
#pragma unroll
        for (int i = 0; i < 4; ++i) {
            int j = bj + wjs + i;
            Bsh[wk][wjs + i] = (kok && j < jmax) ? Wp[i] : 0.f;
        }
        __syncthreads();
#pragma unroll
        for (int kk = 0; kk < 16; ++kk) {
            const float4 av = *reinterpret_cast<const float4*>(&Ash[kk][ty << 2]);
            const float4 bv = *reinterpret_cast<const float4*>(&Bsh[kk][tx << 2]);
            float aa[4] = {av.x, av.y, av.z, av.w};
            float bb[4] = {bv.x, bv.y, bv.z, bv.w};
#pragma unroll
            for (int i = 0; i < 4; ++i)
#pragma unroll
                for (int j = 0; j < 4; ++j)
                    acc[i][j] = fmaf(aa[i], bb[j], acc[i][j]);
        }
        __syncthreads();
    }
#pragma unroll
    for (int i = 0; i < 4; ++i) {
        int row = bm + (ty << 2) + i;
#pragma unroll
        for (int j = 0; j < 4; ++j) {
            int col = bj + (tx << 2) + j;
            if (col < jmax) {
                float v = acc[i][j];
                if (bias) v += bias[col];
                if (ACT == 1) v = fmaxf(v, 0.f);
                if (OBF) ((unsigned short*)Cg)[(size_t)row * ldc + col] = f2bf(v);
                else     ((float*)Cg)[(size_t)row * ldc + col] = v;
            }
        }
    }
}

// fused geom+prior encoder GEMM: z selects input set; bf16 out with relu
__global__ __launch_bounds__(256) void gemm_k2_enc(
    const float* __restrict__ A0, const float* __restrict__ W0, const float* __restrict__ b0,
    const float* __restrict__ A1, const float* __restrict__ W1, const float* __restrict__ b1,
    unsigned short* __restrict__ hb)
{
    __shared__ float Ash[16][64];
    __shared__ float Bsh[16][68];
    int z = blockIdx.z;
    const float* A = z ? A1 : A0;
    const float* W = z ? W1 : W0;
    const float* bias = z ? b1 : b0;
    int K = z ? 50 : 6;
    int colbase = z ? 256 : 128;
    int tid = threadIdx.x;
    int bj = blockIdx.x << 6;
    int bm = blockIdx.y << 6;
    int tx = tid & 15, ty = tid >> 4;
    float acc[4][4] = {};
    int ktn = (K + 15) >> 4;
    int ar = tid >> 2;
    int aks = (tid & 3) << 2;
    int wk = tid >> 4;
    int wjs = (tid & 15) << 2;
    for (int kt = 0; kt < ktn; ++kt) {
        int k0 = kt << 4;
        const float* Ap = A + (size_t)(bm + ar) * K + k0 + aks;
#pragma unroll
        for (int i = 0; i < 4; ++i) {
            int k = k0 + aks + i;
            Ash[aks + i][ar] = (k < K) ? Ap[i] : 0.f;
        }
        const float* Wp = W + (size_t)(k0 + wk) * 128 + bj + wjs;
        bool kok = (k0 + wk) < K;
#pragma unroll
        for (int i = 0; i < 4; ++i)
            Bsh[wk][wjs + i] = kok ? Wp[i] : 0.f;
        __syncthreads();
#pragma unroll
        for (int kk = 0; kk < 16; ++kk) {
            const float4 av = *reinterpret_cast<const float4*>(&Ash[kk][ty << 2]);
            const float4 bv = *reinterpret_cast<const float4*>(&Bsh[kk][tx << 2]);
            float aa[4] = {av.x, av.y, av.z, av.w};
            float bb[4] = {bv.x, bv.y, bv.z, bv.w};
#pragma unroll
            for (int i = 0; i < 4; ++i)
#pragma unroll
                for (int j = 0; j < 4; ++j)
                    acc[i][j] = fmaf(aa[i], bb[j], acc[i][j]);
        }
        __syncthreads();
    }
#pragma unroll
    for (int i = 0; i < 4; ++i) {
        int row = bm + (ty << 2) + i;
#pragma unroll
        for (int j = 0; j < 4; ++j) {
            int col = bj + (tx << 2) + j;
            float v = fmaxf(acc[i][j] + bias[col], 0.f);
            hb[(size_t)row * FF + colbase + col] = f2bf(v);
        }
    }
}

// ================= generic weight transpose + bf16 convert =================
__global__ void transpose_bf(const float* __restrict__ W, unsigned short* __restrict__ Wt,
                             int K, int N, int total) {
    int i = blockIdx.x * 256 + threadIdx.x;
    if (i >= total) return;
    int kn = K * N;
    int z = i / kn, rem = i - z * kn;
    int k = rem / N, n = rem - k * N;
    Wt[(size_t)z * kn + (size_t)n * K + k] = f2bf(W[i]);
}

// both layers' relation weights into wcat rows 0..1151 (row = r*384 + n)
__global__ void transpose2_bf(const float* __restrict__ W1, const float* __restrict__ W2,
                              unsigned short* __restrict__ Wt1, unsigned short* __restrict__ Wt2) {
    int i = blockIdx.x * 256 + threadIdx.x;
    if (i >= 6 * FF * FF) return;
    int z = i / (FF * FF), rem = i - z * (FF * FF);
    int k = rem / FF, n = rem - k * FF;
    const float* W = (z < 3) ? W1 + (size_t)z * FF * FF : W2 + (size_t)(z - 3) * FF * FF;
    unsigned short* Wt = (z < 3) ? Wt1 + (size_t)z * FF * FF : Wt2 + (size_t)(z - 3) * FF * FF;
    Wt[(size_t)n * FF + k] = f2bf(W[(size_t)k * FF + n]);
}

// ================= wqk rows of wcat: row 1152 + r*16 + qk*8 + h =================
__global__ __launch_bounds__(256) void wqk_prep2(
    const float* __restrict__ rw1, const float* __restrict__ q1, const float* __restrict__ k1,
    const float* __restrict__ rw2, const float* __restrict__ q2, const float* __restrict__ k2,
    unsigned short* __restrict__ wqkt1, unsigned short* __restrict__ wqkt2)
{
    __shared__ float qsT[16 * 384];
    int t = threadIdx.x;
    int r = blockIdx.x, ftile = blockIdx.y, layer = blockIdx.z;
    const float* rw = layer ? rw2 : rw1;
    const float* q = layer ? q2 : q1;
    const float* k = layer ? k2 : k1;
    unsigned short* wqkt = layer ? wqkt2 : wqkt1;
    for (int idx = t; idx < 384 * 16; idx += 256) {
        int c = idx >> 4, j = idx & 15;
        qsT[j * 384 + c] = (j < 8) ? q[c * 8 + j] : k[c * 8 + j - 8];
    }
    __syncthreads();
    int j = t & 15, fi = t >> 4;
    const float4* q4 = (const float4*)(qsT + j * 384);
#pragma unroll
    for (int rr = 0; rr < 4; ++rr) {
        int f = ftile * 64 + fi * 4 + rr;
        const float4* a4 = (const float4*)(rw + (size_t)r * FF * FF + (size_t)f * FF);
        float dot = 0.f;
        for (int c4 = 0; c4 < 96; ++c4) {
            float4 a = a4[c4], b = q4[c4];
            dot += a.x * b.x + a.y * b.y + a.z * b.z + a.w * b.w;
        }
        wqkt[(size_t)(r * 16 + j) * FF + f] = f2bf(dot);
    }
}

// ================= CSR build =================
__global__ void csr_count(const int* __restrict__ eo, const int* __restrict__ ea,
                          const int* __restrict__ es, int* __restrict__ deg) {
    int e = blockIdx.x * 256 + threadIdx.x;
    if (e >= ETOT) return;
    int et = e >> 16, le = e & 65535;
    const int* ei = et == 0 ? eo : (et == 1 ? ea : es);
    atomicAdd(&deg[ei[EE + le]], 1);
}
__global__ void csr_alloc(const int* __restrict__ deg, int* __restrict__ counter,
                          int* __restrict__ rps, const int* __restrict__ batch,
                          float* __restrict__ gcnt) {
    int n = blockIdx.x * 256 + threadIdx.x;
    int lane = threadIdx.x & 63;
    int d = (n < NN) ? deg[n] : 0;
    int x = d;
#pragma unroll
    for (int off = 1; off < 64; off <<= 1) {
        int y = __shfl_up(x, off);
        if (lane >= off) x += y;
    }
    int total = __shfl(x, 63);
    int base = 0;
    if (lane == 63) base = atomicAdd(counter, total);
    base = __shfl(base, 63);
    if (n < NN) {
        rps[n] = base + x - d;
        atomicAdd(&gcnt[batch[n]], 1.f);
    }
}
__global__ void csr_fill(const int* __restrict__ eo, const int* __restrict__ ea,
                         const int* __restrict__ es, const int* __restrict__ rps,
                         int* __restrict__ fill, int* __restrict__ elist) {
    int e = blockIdx.x * 256 + threadIdx.x;
    if (e >= ETOT) return;
    int et = e >> 16, le = e & 65535;
    const int* ei = et == 0 ? eo : (et == 1 ? ea : es);
    int src = ei[le], dst = ei[EE + le];
    int pos = rps[dst] + atomicAdd(&fill[dst], 1);
    elist[pos] = (et << 16) | src;
}

// ================= encoder stats over bf16 h: two-stage, no atomics =================
#define ERB 512
__global__ __launch_bounds__(256) void enc_reduce_stage1(const unsigned short* __restrict__ hb, float* __restrict__ pbuf) {
    __shared__ float part[4][6];
    float a1 = 0.f, a2 = 0.f, b1 = 0.f, b2 = 0.f, c1 = 0.f, c2 = 0.f;
    const uint4* h8 = (const uint4*)hb;
    int total8 = NN * FF / 8;
    for (int i = blockIdx.x * 256 + threadIdx.x; i < total8; i += ERB * 256) {
        uint4 v = h8[i];
        float e0 = bflo(v.x), e1 = bfhi(v.x), e2 = bflo(v.y), e3 = bfhi(v.y);
        float e4 = bflo(v.z), e5 = bfhi(v.z), e6 = bflo(v.w), e7 = bfhi(v.w);
        float s1 = e0 + e1 + e2 + e3 + e4 + e5 + e6 + e7;
        float s2 = e0*e0 + e1*e1 + e2*e2 + e3*e3 + e4*e4 + e5*e5 + e6*e6 + e7*e7;
        int enc = (i % 48) >> 4;
        if (enc == 0)      { a1 += s1; a2 += s2; }
        else if (enc == 1) { b1 += s1; b2 += s2; }
        else               { c1 += s1; c2 += s2; }
    }
    a1 = wave_sum(a1); a2 = wave_sum(a2);
    b1 = wave_sum(b1); b2 = wave_sum(b2);
    c1 = wave_sum(c1); c2 = wave_sum(c2);
    int w = threadIdx.x >> 6;
    if ((threadIdx.x & 63) == 0) {
        part[w][0] = a1; part[w][1] = a2; part[w][2] = b1;
        part[w][3] = b2; part[w][4] = c1; part[w][5] = c2;
    }
    __syncthreads();
    if (threadIdx.x < 6) {
        float s = part[0][threadIdx.x] + part[1][threadIdx.x] + part[2][threadIdx.x] + part[3][threadIdx.x];
        pbuf[blockIdx.x * 6 + threadIdx.x] = s;
    }
}

__global__ void enc_reduce_stage2(const float* __restrict__ pbuf, float* __restrict__ est) {
    int lane = threadIdx.x;
    float s[6] = {};
    for (int b = lane; b < ERB; b += 64)
#pragma unroll
        for (int j = 0; j < 6; ++j) s[j] += pbuf[b * 6 + j];
#pragma unroll
    for (int j = 0; j < 6; ++j) {
        float v = wave_sum(s[j]);
        if (lane == 0) est[j] = v;
    }
    __syncthreads();
    if (lane < 3) {
        float cnt = (float)NN * 128.f;
        float mean = est[2 * lane] / cnt;
        float var = est[2 * lane + 1] / cnt - mean * mean;
        var = fmaxf(var, 0.f);
        est[6 + 2 * lane] = mean;
        est[7 + 2 * lane] = 1.f / (sqrtf(var) + 1e-5f);
    }
}

__global__ __launch_bounds__(256) void enc_apply(
    unsigned short* __restrict__ hb, const float* __restrict__ est,
    const float* __restrict__ lw0, const float* __restrict__ lb0,
    const float* __restrict__ lw1, const float* __restrict__ lb1,
    const float* __restrict__ lw2, const float* __restrict__ lb2)
{
    long gt = (long)blockIdx.x * 256 + threadIdx.x;
    if (gt >= (long)NN * FF) return;
    int f = (int)(gt % FF);
    int enc = f >> 7, j = f & 127;
    const float* lw = enc == 0 ? lw0 : (enc == 1 ? lw1 : lw2);
    const float* lb = enc == 0 ? lb0 : (enc == 1 ? lb1 : lb2);
    float mean = est[6 + 2 * enc], sc = est[7 + 2 * enc];
    float v = (bflo((unsigned)hb[gt]) - mean) * sc * lw[j] + lb[j];
    hb[gt] = f2bf(v);
}

// ================= single-pass softmax + gather + elu + residual + stats =================
__global__ __launch_bounds__(256) void gather_fused(
    const int* __restrict__ rps, const int* __restrict__ deg, const int* __restrict__ elist,
    const float* __restrict__ qkbuf, const unsigned short* __restrict__ xt,
    const unsigned short* __restrict__ hbin, const float* __restrict__ rb, const int* __restrict__ batch,
    float* __restrict__ gs1, float* __restrict__ gs2, unsigned short* __restrict__ ybuf)
{
    int node = blockIdx.x * 4 + (threadIdx.x >> 6);
    int lane = threadIdx.x & 63;
    bool act = lane < 48;
    int d = deg[node], rp = rps[node];
    int head = lane / 6; if (head > 7) head = 7;
    float qd0 = qkbuf[(size_t)node * 48 + 0 + head];
    float qd1 = qkbuf[(size_t)node * 48 + 16 + head];
    float qd2 = qkbuf[(size_t)node * 48 + 32 + head];
    uint4 hu = {0, 0, 0, 0};
    if (act) hu = *((const uint4*)(hbin + (size_t)node * FF) + lane);
    float s = 0.f;
    float a0 = 0.f, a1 = 0.f, a2 = 0.f, a3 = 0.f, a4 = 0.f, a5 = 0.f, a6 = 0.f, a7 = 0.f;
    for (int base = 0; base < d; base += 64) {
        int myp = (base + lane < d) ? elist[rp + base + lane] : 0;
        int lim = d - base; if (lim > 64) lim = 64;
        for (int e = 0; e < lim; ++e) {
            int packed = __shfl(myp, e);
            int et = packed >> 16, src = packed & 0xFFFF;
            uint4 u = {0, 0, 0, 0};
            if (act) u = *((const uint4*)(xt + ((size_t)et * NN + src) * FF) + lane);
            float qd = et == 0 ? qd0 : (et == 1 ? qd1 : qd2);
            float a = qd + qkbuf[(size_t)src * 48 + et * 16 + 8 + head];
            a = a >= 0.f ? a : NEG_SLOPE * a;
            float pw = __expf(a);
            s += pw;
            a0 = fmaf(pw, bflo(u.x), a0); a1 = fmaf(pw, bfhi(u.x), a1);
            a2 = fmaf(pw, bflo(u.y), a2); a3 = fmaf(pw, bfhi(u.y), a3);
            a4 = fmaf(pw, bflo(u.z), a4); a5 = fmaf(pw, bfhi(u.z), a5);
            a6 = fmaf(pw, bflo(u.w), a6); a7 = fmaf(pw, bfhi(u.w), a7);
        }
    }
    float inv = 1.f / (s + 1e-16f);
    float hv[8] = {bflo(hu.x), bfhi(hu.x), bflo(hu.y), bfhi(hu.y),
                   bflo(hu.z), bfhi(hu.z), bflo(hu.w), bfhi(hu.w)};
    float av[8] = {a0, a1, a2, a3, a4, a5, a6, a7};
    int f0 = lane * 8;
    float s1 = 0.f, s2 = 0.f;
    if (act) {
        float yv[8];
#pragma unroll
        for (int i = 0; i < 8; ++i) {
            float mv = av[i] * inv + rb[f0 + i];
            float e = mv > 0.f ? mv : (__expf(mv) - 1.f);
            float y = hv[i] + e;
            yv[i] = y;
            s1 += y; s2 += y * y;
        }
        uint4 pkv;
        pkv.x = pk2(yv[0], yv[1]); pkv.y = pk2(yv[2], yv[3]);
        pkv.z = pk2(yv[4], yv[5]); pkv.w = pk2(yv[6], yv[7]);
        *((uint4*)(ybuf + (size_t)node * FF) + lane) = pkv;
    }
    s1 = wave_sum(s1);
    s2 = wave_sum(s2);
    if (lane == 0) {
        int g = batch[node];
        atomicAdd(&gs1[g], s1);
        atomicAdd(&gs2[g], s2);
    }
}

// ================= LN apply with inline per-graph finalize =================
__global__ __launch_bounds__(256) void ln_apply(
    const unsigned short* __restrict__ y, const int* __restrict__ batch,
    const float* __restrict__ gcnt, const float* __restrict__ gs1, const float* __restrict__ gs2,
    const float* __restrict__ w, const float* __restrict__ b,
    unsigned short* __restrict__ hbOut)
{
    long gt = (long)blockIdx.x * 256 + threadIdx.x;
    int n = (int)(gt >> 6);
    if (n >= NN) return;
    int lane = (int)(gt & 63);
    int f0 = lane * 6;
    int g = batch[n];
    float cnt = fmaxf(gcnt[g], 1.f) * (float)FF;
    float mean = gs1[g] / cnt;
    float var = fmaxf(gs2[g] / cnt - mean * mean, 0.f);
    float rs = 1.f / sqrtf(var + 1e-5f);
    const unsigned* yr = (const unsigned*)(y + (size_t)n * FF) + lane * 3;
    unsigned u0 = yr[0], u1 = yr[1], u2 = yr[2];
    float yv[6] = {bflo(u0), bfhi(u0), bflo(u1), bfhi(u1), bflo(u2), bfhi(u2)};
    float ov[6];
#pragma unroll
    for (int i = 0; i < 6; ++i)
        ov[i] = (yv[i] - mean) * rs * w[f0 + i] + b[f0 + i];
    unsigned* orow = (unsigned*)(hbOut + (size_t)n * FF) + lane * 3;
    orow[0] = pk2(ov[0], ov[1]);
    orow[1] = pk2(ov[2], ov[3]);
    orow[2] = pk2(ov[4], ov[5]);
}

// ================= host-side layer driver =================
static void rgat_layer(hipStream_t stream,
    const unsigned short* hbIn,
    const float* rb, const float* lnw, const float* lnb,
    const int* rps, const int* deg, const int* elist, const int* batch,
    const unsigned short* wcat, unsigned short* xt, float* qkbuf,
    float* gs, const float* gcnt,
    unsigned short* ybuf, unsigned short* hbOut)
{
    gemm_rel<<<dim3(10, 384, 1), 256, 0, stream>>>(hbIn, wcat, xt, qkbuf);
    gather_fused<<<NN / 4, 256, 0, stream>>>(rps, deg, elist, qkbuf, xt, hbIn, rb, batch,
                                             gs, gs + GG, ybuf);
    ln_apply<<<NN / 4, 256, 0, stream>>>(ybuf, batch, gcnt, gs, gs + GG, lnw, lnb, hbOut);
}

extern "C" void kernel_launch(void* const* d_in, const int* in_sizes, int n_in,
                              void* d_out, int out_size, void* d_ws, size_t ws_size,
                              hipStream_t stream)
{
    const float* x_visual = (const float*)d_in[0];
    const float* x_geom   = (const float*)d_in[1];
    const float* x_prior  = (const float*)d_in[2];
    const float* vis_w  = (const float*)d_in[3];
    const float* vis_b  = (const float*)d_in[4];
    const float* vis_lw = (const float*)d_in[5];
    const float* vis_lb = (const float*)d_in[6];
    const float* geom_w  = (const float*)d_in[7];
    const float* geom_b  = (const float*)d_in[8];
    const float* geom_lw = (const float*)d_in[9];
    const float* geom_lb = (const float*)d_in[10];
    const float* prior_w  = (const float*)d_in[11];
    const float* prior_b  = (const float*)d_in[12];
    const float* prior_lw = (const float*)d_in[13];
    const float* prior_lb = (const float*)d_in[14];
    const float* r1_w = (const float*)d_in[15];
    const float* r1_q = (const float*)d_in[16];
    const float* r1_k = (const float*)d_in[17];
    const float* r1_b = (const float*)d_in[18];
    const float* n1_w = (const float*)d_in[19];
    const float* n1_b = (const float*)d_in[20];
    const float* r2_w = (const float*)d_in[21];
    const float* r2_q = (const float*)d_in[22];
    const float* r2_k = (const float*)d_in[23];
    const float* r2_b = (const float*)d_in[24];
    const float* n2_w = (const float*)d_in[25];
    const float* n2_b = (const float*)d_in[26];
    const float* c_w1 = (const float*)d_in[27];
    const float* c_b1 = (const float*)d_in[28];
    const float* c_w2 = (const float*)d_in[29];
    const float* c_b2 = (const float*)d_in[30];
    const int* ei_o  = (const int*)d_in[31];
    const int* ei_a  = (const int*)d_in[32];
    const int* ei_s  = (const int*)d_in[33];
    const int* batch = (const int*)d_in[34];
    float* out = (float*)d_out;

    char* p = (char*)d_ws;
    auto alloc = [&](size_t bytes) { char* r = p; p += (bytes + 255) & ~(size_t)255; return r; };
    unsigned short* hbA = (unsigned short*)alloc((size_t)NN * FF * 2);
    unsigned short* hbB = (unsigned short*)alloc((size_t)NN * FF * 2);
    unsigned short* ybuf = (unsigned short*)alloc((size_t)NN * FF * 2);
    unsigned short* xt = (unsigned short*)alloc((size_t)3 * NN * FF * 2);
    unsigned short* wcat1 = (unsigned short*)alloc((size_t)1280 * FF * 2);
    unsigned short* wcat2 = (unsigned short*)alloc((size_t)1280 * FF * 2);
    unsigned short* wtv = (unsigned short*)alloc((size_t)1024 * 128 * 2);
    unsigned short* wtc = (unsigned short*)alloc((size_t)FF * 128 * 2);
    float* qkbuf = (float*)alloc((size_t)NN * 48 * 4);
    float* t128 = (float*)alloc((size_t)NN * 128 * 4);
    int* rps = (int*)alloc(NN * 4);
    int* elist = (int*)alloc(ETOT * 4);
    float* est = (float*)alloc(64);
    float* pbuf = (float*)alloc(ERB * 6 * 4);
    // ---- contiguous zero-init region (one memset) ----
    char* z0 = alloc((size_t)2 * NN * 4 + 256 + (size_t)4 * GG * 4 + GG * 4);
    int* deg = (int*)z0;
    int* fill = deg + NN;
    int* counter = (int*)(z0 + (size_t)2 * NN * 4);
    float* gs = (float*)(z0 + (size_t)2 * NN * 4 + 256);
    float* gcnt = gs + 4 * GG;
    hipMemsetAsync(z0, 0, (size_t)2 * NN * 4 + 256 + (size_t)4 * GG * 4 + GG * 4, stream);

    // ---- CSR build + per-graph node counts ----
    csr_count<<<ETOT / 256, 256, 0, stream>>>(ei_o, ei_a, ei_s, deg);
    csr_alloc<<<NN / 256, 256, 0, stream>>>(deg, counter, rps, batch, gcnt);
    csr_fill<<<ETOT / 256, 256, 0, stream>>>(ei_o, ei_a, ei_s, rps, fill, elist);

    // ---- all weight prep up front ----
    transpose2_bf<<<(6 * FF * FF + 255) / 256, 256, 0, stream>>>(r1_w, r2_w, wcat1, wcat2);
    wqk_prep2<<<dim3(3, 6, 2), 256, 0, stream>>>(r1_w, r1_q, r1_k, r2_w, r2_q, r2_k,
                                                 wcat1 + (size_t)1152 * FF, wcat2 + (size_t)1152 * FF);
    transpose_bf<<<(1024 * 128 + 255) / 256, 256, 0, stream>>>(vis_w, wtv, 1024, 128, 1024 * 128);
    transpose_bf<<<(FF * 128 + 255) / 256, 256, 0, stream>>>(c_w1, wtc, FF, 128, FF * 128);

    // ---- encoders (all-bf16 h) ----
    gemm_mfma<1, false, true><<<dim3(384, 1, 1), 256, 0, stream>>>(
        x_visual, 1024, wtv, vis_b, hbA, FF);
    gemm_k2_enc<<<dim3(2, 768, 2), 256, 0, stream>>>(
        x_geom, geom_w, geom_b, x_prior, prior_w, prior_b, hbA);
    enc_reduce_stage1<<<ERB, 256, 0, stream>>>(hbA, pbuf);
    enc_reduce_stage2<<<1, 64, 0, stream>>>(pbuf, est);
    enc_apply<<<(int)((size_t)NN * FF / 256), 256, 0, stream>>>(
        hbA, est, vis_lw, vis_lb, geom_lw, geom_lb, prior_lw, prior_lb);

    // ---- RGAT layers (bf16 ping-pong hbA -> hbB -> hbA) ----
    rgat_layer(stream, hbA, r1_b, n1_w, n1_b, rps, deg, elist, batch,
               wcat1, xt, qkbuf, gs, gcnt, ybuf, hbB);
    rgat_layer(stream, hbB, r2_b, n2_w, n2_b, rps, deg, elist, batch,
               wcat2, xt, qkbuf, gs + 2 * GG, gcnt, ybuf, hbA);

    // ---- classifier ----
    gemm_mfma<1, true, false><<<dim3(384, 1, 1), 256, 0, stream>>>(
        hbA, FF, wtc, c_b1, t128, 128);
    gemm_k<0, false><<<dim3(1, 768, 1), 256, 0, stream>>>(t128, 128, c_w2, 49, c_b2, out, 49, 49);
}

// Round 15
// 685.148 us; speedup vs baseline: 1.0267x; 1.0267x over previous
//
#include <hip/hip_runtime.h>
#include <hip/hip_bf16.h>

#define NN 49152
#define GG 1024
#define EE 65536
#define ETOT 196608
#define FF 384
#define NEG_SLOPE 0.2f

typedef __attribute__((ext_vector_type(8))) short bf16x8;
typedef __attribute__((ext_vector_type(4))) float f32x4;

__device__ __forceinline__ float wave_sum(float v) {
#pragma unroll
    for (int m = 32; m; m >>= 1) v += __shfl_xor(v, m);
    return v;
}
__device__ __forceinline__ unsigned short f2bf(float f) {
    __hip_bfloat16 b = __float2bfloat16(f);
    return *reinterpret_cast<unsigned short*>(&b);
}
__device__ __forceinline__ float bflo(unsigned u) { return __uint_as_float(u << 16); }
__device__ __forceinline__ float bfhi(unsigned u) { return __uint_as_float(u & 0xffff0000u); }
__device__ __forceinline__ unsigned pk2(float lo, float hi) {
    return ((unsigned)f2bf(hi) << 16) | (unsigned)f2bf(lo);
}

__device__ __forceinline__ void gload_lds16(const void* g, void* l) {
    __builtin_amdgcn_global_load_lds(
        (const __attribute__((address_space(1))) unsigned int*)g,
        (__attribute__((address_space(3))) unsigned int*)l, 16, 0, 0);
}

// ================= MFMA bf16 GEMM: C = act(A @ Bt^T + bias) =================
// Grid: x = M-tiles, y = N-tiles, z = batch.
__device__ __forceinline__ int swz(int row, int c16) {
    return row * 64 + ((c16 ^ ((row >> 1) & 3)) << 4);
}

template <int ACT, bool ABF, bool OBF>
__global__ __launch_bounds__(256) void gemm_mfma(
    const void* __restrict__ Ag, int K,
    const unsigned short* __restrict__ Btg,
    const float* __restrict__ bias,
    void* __restrict__ Cg, int ldc,
    size_t bzs, size_t czs)
{
    __shared__ __align__(16) char As[8192];
    __shared__ __align__(16) char Bs[8192];
    const unsigned short* Bt = Btg + (size_t)blockIdx.z * bzs;
    int t = threadIdx.x;
    int bm = blockIdx.x << 7, bn = blockIdx.y << 7;
    int lane = t & 63, wid = t >> 6, wr = wid >> 1, wc = wid & 1;
    f32x4 acc[4][4] = {};
    int ktn = K >> 5;
    for (int kt = 0; kt < ktn; ++kt) {
        int k0 = kt << 5;
#pragma unroll
        for (int ii = 0; ii < 2; ++ii) {
            int id = t + (ii << 8);
            int row = id >> 2, c = id & 3;
            int csrc = c ^ ((row >> 1) & 3);
            size_t ldsoff = (size_t)((wid << 10) + (ii << 12));
            if (ABF) {
                const unsigned short* srcA = (const unsigned short*)Ag + (size_t)(bm + row) * K + k0 + csrc * 8;
                gload_lds16(srcA, As + ldsoff);
            } else {
                const float* srcA = (const float*)Ag + (size_t)(bm + row) * K + k0 + c * 8;
                float4 a0 = *(const float4*)srcA;
                float4 a1 = *(const float4*)(srcA + 4);
                union { unsigned short u[8]; int4 v; } P;
                P.u[0] = f2bf(a0.x); P.u[1] = f2bf(a0.y); P.u[2] = f2bf(a0.z); P.u[3] = f2bf(a0.w);
                P.u[4] = f2bf(a1.x); P.u[5] = f2bf(a1.y); P.u[6] = f2bf(a1.z); P.u[7] = f2bf(a1.w);
                *(int4*)(As + swz(row, c)) = P.v;
            }
            const unsigned short* srcB = Bt + (size_t)(bn + row) * K + k0 + csrc * 8;
            gload_lds16(srcB, Bs + ldsoff);
        }
        __syncthreads();
        int c16 = lane >> 4;
        bf16x8 af[4], bfr[4];
#pragma unroll
        for (int m = 0; m < 4; ++m)
            af[m] = *(const bf16x8*)(As + swz((wr << 6) + (m << 4) + (lane & 15), c16));
#pragma unroll
        for (int n = 0; n < 4; ++n)
            bfr[n] = *(const bf16x8*)(Bs + swz((wc << 6) + (n << 4) + (lane & 15), c16));
#pragma unroll
        for (int m = 0; m < 4; ++m)
#pragma unroll
            for (int n = 0; n < 4; ++n)
                acc[m][n] = __builtin_amdgcn_mfma_f32_16x16x32_bf16(af[m], bfr[n], acc[m][n], 0, 0, 0);
        __syncthreads();
    }
#pragma unroll
    for (int m = 0; m < 4; ++m) {
#pragma unroll
        for (int n = 0; n < 4; ++n) {
            int row0 = bm + (wr << 6) + (m << 4) + ((lane >> 4) << 2);
            int col = bn + (wc << 6) + (n << 4) + (lane & 15);
            float bv = bias ? bias[col] : 0.f;
#pragma unroll
            for (int j = 0; j < 4; ++j) {
                float v = acc[m][n][j] + bv;
                if (ACT == 1) v = fmaxf(v, 0.f);
                if (OBF) {
                    unsigned short* C = (unsigned short*)Cg + (size_t)blockIdx.z * czs;
                    C[(size_t)(row0 + j) * ldc + col] = f2bf(v);
                } else {
                    float* C = (float*)Cg + (size_t)blockIdx.z * czs;
                    C[(size_t)(row0 + j) * ldc + col] = v;
                }
            }
        }
    }
}

// ================= f32-input fallback GEMM (small K / small N), optional bf16 out =================
template <int ACT, bool OBF>
__global__ __launch_bounds__(256) void gemm_k(
    const float* __restrict__ A, int K,
    const float* __restrict__ W, int Jw,
    const float* __restrict__ bias,
    void* __restrict__ Cg, int ldc, int jmax)
{
    __shared__ float Ash[16][64];
    __shared__ float Bsh[16][68];
    int tid = threadIdx.x;
    int bj = blockIdx.x << 6;
    int bm = blockIdx.y << 6;
    int tx = tid & 15, ty = tid >> 4;
    float acc[4][4] = {};
    int ktn = (K + 15) >> 4;
    int ar = tid >> 2;
    int aks = (tid & 3) << 2;
    int wk = tid >> 4;
    int wjs = (tid & 15) << 2;
    for (int kt = 0; kt < ktn; ++kt) {
        int k0 = kt << 4;
        const float* Ap = A + (size_t)(bm + ar) * K + k0 + aks;
#pragma unroll
        for (int i = 0; i < 4; ++i) {
            int k = k0 + aks + i;
            Ash[aks + i][ar] = (k < K) ? Ap[i] : 0.f;
        }
        const float* Wp = W + (size_t)(k0 + wk) * Jw + bj + wjs;
        bool kok = (k0 + wk) < K;
#pragma unroll
        for (int i = 0; i < 4; ++i) {
            int j = bj + wjs + i;
            Bsh[wk][wjs + i] = (kok && j < jmax) ? Wp[i] : 0.f;
        }
        __syncthreads();
#pragma unroll
        for (int kk = 0; kk < 16; ++kk) {
            const float4 av = *reinterpret_cast<const float4*>(&Ash[kk][ty << 2]);
            const float4 bv = *reinterpret_cast<const float4*>(&Bsh[kk][tx << 2]);
            float aa[4] = {av.x, av.y, av.z, av.w};
            float bb[4] = {bv.x, bv.y, bv.z, bv.w};
#pragma unroll
            for (int i = 0; i < 4; ++i)
#pragma unroll
                for (int j = 0; j < 4; ++j)
                    acc[i][j] = fmaf(aa[i], bb[j], acc[i][j]);
        }
        __syncthreads();
    }
#pragma unroll
    for (int i = 0; i < 4; ++i) {
        int row = bm + (ty << 2) + i;
#pragma unroll
        for (int j = 0; j < 4; ++j) {
            int col = bj + (tx << 2) + j;
            if (col < jmax) {
                float v = acc[i][j];
                if (bias) v += bias[col];
                if (ACT == 1) v = fmaxf(v, 0.f);
                if (OBF) ((unsigned short*)Cg)[(size_t)row * ldc + col] = f2bf(v);
                else     ((float*)Cg)[(size_t)row * ldc + col] = v;
            }
        }
    }
}

// fused geom+prior encoder GEMM: z selects input set; bf16 out with relu
__global__ __launch_bounds__(256) void gemm_k2_enc(
    const float* __restrict__ A0, const float* __restrict__ W0, const float* __restrict__ b0,
    const float* __restrict__ A1, const float* __restrict__ W1, const float* __restrict__ b1,
    unsigned short* __restrict__ hb)
{
    __shared__ float Ash[16][64];
    __shared__ float Bsh[16][68];
    int z = blockIdx.z;
    const float* A = z ? A1 : A0;
    const float* W = z ? W1 : W0;
    const float* bias = z ? b1 : b0;
    int K = z ? 50 : 6;
    int colbase = z ? 256 : 128;
    int tid = threadIdx.x;
    int bj = blockIdx.x << 6;
    int bm = blockIdx.y << 6;
    int tx = tid & 15, ty = tid >> 4;
    float acc[4][4] = {};
    int ktn = (K + 15) >> 4;
    int ar = tid >> 2;
    int aks = (tid & 3) << 2;
    int wk = tid >> 4;
    int wjs = (tid & 15) << 2;
    for (int kt = 0; kt < ktn; ++kt) {
        int k0 = kt << 4;
        const float* Ap = A + (size_t)(bm + ar) * K + k0 + aks;
#pragma unroll
        for (int i = 0; i < 4; ++i) {
            int k = k0 + aks + i;
            Ash[aks + i][ar] = (k < K) ? Ap[i] : 0.f;
        }
        const float* Wp = W + (size_t)(k0 + wk) * 128 + bj + wjs;
        bool kok = (k0 + wk) < K;
#pragma unroll
        for (int i = 0; i < 4; ++i)
            Bsh[wk][wjs + i] = kok ? Wp[i] : 0.f;
        __syncthreads();
#pragma unroll
        for (int kk = 0; kk < 16; ++kk) {
            const float4 av = *reinterpret_cast<const float4*>(&Ash[kk][ty << 2]);
            const float4 bv = *reinterpret_cast<const float4*>(&Bsh[kk][tx << 2]);
            float aa[4] = {av.x, av.y, av.z, av.w};
            float bb[4] = {bv.x, bv.y, bv.z, bv.w};
#pragma unroll
            for (int i = 0; i < 4; ++i)
#pragma unroll
                for (int j = 0; j < 4; ++j)
                    acc[i][j] = fmaf(aa[i], bb[j], acc[i][j]);
        }
        __syncthreads();
    }
#pragma unroll
    for (int i = 0; i < 4; ++i) {
        int row = bm + (ty << 2) + i;
#pragma unroll
        for (int j = 0; j < 4; ++j) {
            int col = bj + (tx << 2) + j;
            float v = fmaxf(acc[i][j] + bias[col], 0.f);
            hb[(size_t)row * FF + colbase + col] = f2bf(v);
        }
    }
}

// ================= generic weight transpose + bf16 convert =================
__global__ void transpose_bf(const float* __restrict__ W, unsigned short* __restrict__ Wt,
                             int K, int N, int total) {
    int i = blockIdx.x * 256 + threadIdx.x;
    if (i >= total) return;
    int kn = K * N;
    int z = i / kn, rem = i - z * kn;
    int k = rem / N, n = rem - k * N;
    Wt[(size_t)z * kn + (size_t)n * K + k] = f2bf(W[i]);
}

// both layers' relation weights in one launch: 6 z-slices of [384][384]
__global__ void transpose2_bf(const float* __restrict__ W1, const float* __restrict__ W2,
                              unsigned short* __restrict__ Wt1, unsigned short* __restrict__ Wt2) {
    int i = blockIdx.x * 256 + threadIdx.x;
    if (i >= 6 * FF * FF) return;
    int z = i / (FF * FF), rem = i - z * (FF * FF);
    int k = rem / FF, n = rem - k * FF;
    const float* W = (z < 3) ? W1 + (size_t)z * FF * FF : W2 + (size_t)(z - 3) * FF * FF;
    unsigned short* Wt = (z < 3) ? Wt1 + (size_t)z * FF * FF : Wt2 + (size_t)(z - 3) * FF * FF;
    Wt[(size_t)n * FF + k] = f2bf(W[(size_t)k * FF + n]);
}

// ================= wqkt[r*16 + qk*8 + h][f] = sum_c rw[r][f][c] * (qk?k:q)[c][h] =================
__global__ __launch_bounds__(256) void wqk_prep2(
    const float* __restrict__ rw1, const float* __restrict__ q1, const float* __restrict__ k1,
    const float* __restrict__ rw2, const float* __restrict__ q2, const float* __restrict__ k2,
    unsigned short* __restrict__ wqkt1, unsigned short* __restrict__ wqkt2)
{
    __shared__ float qsT[16 * 384];
    int t = threadIdx.x;
    int r = blockIdx.x, ftile = blockIdx.y, layer = blockIdx.z;
    const float* rw = layer ? rw2 : rw1;
    const float* q = layer ? q2 : q1;
    const float* k = layer ? k2 : k1;
    unsigned short* wqkt = layer ? wqkt2 : wqkt1;
    for (int idx = t; idx < 384 * 16; idx += 256) {
        int c = idx >> 4, j = idx & 15;
        qsT[j * 384 + c] = (j < 8) ? q[c * 8 + j] : k[c * 8 + j - 8];
    }
    __syncthreads();
    int j = t & 15, fi = t >> 4;
    const float4* q4 = (const float4*)(qsT + j * 384);
#pragma unroll
    for (int rr = 0; rr < 4; ++rr) {
        int f = ftile * 64 + fi * 4 + rr;
        const float4* a4 = (const float4*)(rw + (size_t)r * FF * FF + (size_t)f * FF);
        float dot = 0.f;
        for (int c4 = 0; c4 < 96; ++c4) {
            float4 a = a4[c4], b = q4[c4];
            dot += a.x * b.x + a.y * b.y + a.z * b.z + a.w * b.w;
        }
        wqkt[(size_t)(r * 16 + j) * FF + f] = f2bf(dot);
    }
}

// ================= CSR build =================
__global__ void csr_count(const int* __restrict__ eo, const int* __restrict__ ea,
                          const int* __restrict__ es, int* __restrict__ deg) {
    int e = blockIdx.x * 256 + threadIdx.x;
    if (e >= ETOT) return;
    int et = e >> 16, le = e & 65535;
    const int* ei = et == 0 ? eo : (et == 1 ? ea : es);
    atomicAdd(&deg[ei[EE + le]], 1);
}
__global__ void csr_alloc(const int* __restrict__ deg, int* __restrict__ counter,
                          int* __restrict__ rps, const int* __restrict__ batch,
                          float* __restrict__ gcnt) {
    int n = blockIdx.x * 256 + threadIdx.x;
    int lane = threadIdx.x & 63;
    int d = (n < NN) ? deg[n] : 0;
    int x = d;
#pragma unroll
    for (int off = 1; off < 64; off <<= 1) {
        int y = __shfl_up(x, off);
        if (lane >= off) x += y;
    }
    int total = __shfl(x, 63);
    int base = 0;
    if (lane == 63) base = atomicAdd(counter, total);
    base = __shfl(base, 63);
    if (n < NN) {
        rps[n] = base + x - d;
        atomicAdd(&gcnt[batch[n]], 1.f);
    }
}
__global__ void csr_fill(const int* __restrict__ eo, const int* __restrict__ ea,
                         const int* __restrict__ es, const int* __restrict__ rps,
                         int* __restrict__ fill, int* __restrict__ elist) {
    int e = blockIdx.x * 256 + threadIdx.x;
    if (e >= ETOT) return;
    int et = e >> 16, le = e & 65535;
    const int* ei = et == 0 ? eo : (et == 1 ? ea : es);
    int src = ei[le], dst = ei[EE + le];
    int pos = rps[dst] + atomicAdd(&fill[dst], 1);
    elist[pos] = (et << 16) | src;
}

// ================= encoder stats over bf16 h: two-stage, no atomics =================
#define ERB 512
__global__ __launch_bounds__(256) void enc_reduce_stage1(const unsigned short* __restrict__ hb, float* __restrict__ pbuf) {
    __shared__ float part[4][6];
    float a1 = 0.f, a2 = 0.f, b1 = 0.f, b2 = 0.f, c1 = 0.f, c2 = 0.f;
    const uint4* h8 = (const uint4*)hb;
    int total8 = NN * FF / 8;
    for (int i = blockIdx.x * 256 + threadIdx.x; i < total8; i += ERB * 256) {
        uint4 v = h8[i];
        float e0 = bflo(v.x), e1 = bfhi(v.x), e2 = bflo(v.y), e3 = bfhi(v.y);
        float e4 = bflo(v.z), e5 = bfhi(v.z), e6 = bflo(v.w), e7 = bfhi(v.w);
        float s1 = e0 + e1 + e2 + e3 + e4 + e5 + e6 + e7;
        float s2 = e0*e0 + e1*e1 + e2*e2 + e3*e3 + e4*e4 + e5*e5 + e6*e6 + e7*e7;
        int enc = (i % 48) >> 4;
        if (enc == 0)      { a1 += s1; a2 += s2; }
        else if (enc == 1) { b1 += s1; b2 += s2; }
        else               { c1 += s1; c2 += s2; }
    }
    a1 = wave_sum(a1); a2 = wave_sum(a2);
    b1 = wave_sum(b1); b2 = wave_sum(b2);
    c1 = wave_sum(c1); c2 = wave_sum(c2);
    int w = threadIdx.x >> 6;
    if ((threadIdx.x & 63) == 0) {
        part[w][0] = a1; part[w][1] = a2; part[w][2] = b1;
        part[w][3] = b2; part[w][4] = c1; part[w][5] = c2;
    }
    __syncthreads();
    if (threadIdx.x < 6) {
        float s = part[0][threadIdx.x] + part[1][threadIdx.x] + part[2][threadIdx.x] + part[3][threadIdx.x];
        pbuf[blockIdx.x * 6 + threadIdx.x] = s;
    }
}

__global__ void enc_reduce_stage2(const float* __restrict__ pbuf, float* __restrict__ est) {
    int lane = threadIdx.x;
    float s[6] = {};
    for (int b = lane; b < ERB; b += 64)
#pragma unroll
        for (int j = 0; j < 6; ++j) s[j] += pbuf[b * 6 + j];
#pragma unroll
    for (int j = 0; j < 6; ++j) {
        float v = wave_sum(s[j]);
        if (lane == 0) est[j] = v;
    }
    __syncthreads();
    if (lane < 3) {
        float cnt = (float)NN * 128.f;
        float mean = est[2 * lane] / cnt;
        float var = est[2 * lane + 1] / cnt - mean * mean;
        var = fmaxf(var, 0.f);
        est[6 + 2 * lane] = mean;
        est[7 + 2 * lane] = 1.f / (sqrtf(var) + 1e-5f);
    }
}

// 48 lanes x 8 features (one uint4 each); 8 | 128 so a lane never straddles an encoder block
__global__ __launch_bounds__(256) void enc_apply(
    unsigned short* __restrict__ hb, const float* __restrict__ est,
    const float* __restrict__ lw0, const float* __restrict__ lb0,
    const float* __restrict__ lw1, const float* __restrict__ lb1,
    const float* __restrict__ lw2, const float* __restrict__ lb2)
{
    int n = blockIdx.x * 4 + (threadIdx.x >> 6);
    int lane = threadIdx.x & 63;
    if (lane >= 48 || n >= NN) return;
    int f0 = lane * 8;
    int enc = f0 >> 7;
    int j0 = f0 & 127;
    const float* lw = enc == 0 ? lw0 : (enc == 1 ? lw1 : lw2);
    const float* lb = enc == 0 ? lb0 : (enc == 1 ? lb1 : lb2);
    float mean = est[6 + 2 * enc], sc = est[7 + 2 * enc];
    uint4 u = *((const uint4*)(hb + (size_t)n * FF) + lane);
    float v[8] = {bflo(u.x), bfhi(u.x), bflo(u.y), bfhi(u.y),
                  bflo(u.z), bfhi(u.z), bflo(u.w), bfhi(u.w)};
    float o[8];
#pragma unroll
    for (int i = 0; i < 8; ++i)
        o[i] = (v[i] - mean) * sc * lw[j0 + i] + lb[j0 + i];
    uint4 pkv;
    pkv.x = pk2(o[0], o[1]); pkv.y = pk2(o[2], o[3]);
    pkv.z = pk2(o[4], o[5]); pkv.w = pk2(o[6], o[7]);
    *((uint4*)(hb + (size_t)n * FF) + lane) = pkv;
}

// ================= qkbuf via MFMA: [N,384] @ [384,48] from h directly =================
__global__ __launch_bounds__(256) void qk48_mfma(
    const unsigned short* __restrict__ hb,
    const unsigned short* __restrict__ wqkt,
    float* __restrict__ qkbuf)
{
    __shared__ __align__(16) unsigned short wlds[48 * 392];
    int t = threadIdx.x;
    for (int idx = t; idx < 48 * 192; idx += 256) {
        int row = idx / 192, dw = idx - row * 192;
        *((unsigned*)(wlds + row * 392) + dw) = ((const unsigned*)wqkt)[row * 192 + dw];
    }
    __syncthreads();
    int lane = t & 63, wid = t >> 6;
    int col = lane & 15, kq = lane >> 4;
    int tile = blockIdx.x * 4 + wid;
    const unsigned short* arow = hb + (size_t)(tile * 16 + col) * FF + kq * 8;
    f32x4 acc0 = {}, acc1 = {}, acc2 = {};
#pragma unroll
    for (int kt = 0; kt < 12; ++kt) {
        bf16x8 af = *(const bf16x8*)(arow + kt * 32);
        bf16x8 b0 = *(const bf16x8*)(wlds + (0 * 16 + col) * 392 + kt * 32 + kq * 8);
        bf16x8 b1 = *(const bf16x8*)(wlds + (1 * 16 + col) * 392 + kt * 32 + kq * 8);
        bf16x8 b2 = *(const bf16x8*)(wlds + (2 * 16 + col) * 392 + kt * 32 + kq * 8);
        acc0 = __builtin_amdgcn_mfma_f32_16x16x32_bf16(af, b0, acc0, 0, 0, 0);
        acc1 = __builtin_amdgcn_mfma_f32_16x16x32_bf16(af, b1, acc1, 0, 0, 0);
        acc2 = __builtin_amdgcn_mfma_f32_16x16x32_bf16(af, b2, acc2, 0, 0, 0);
    }
    int row0 = kq << 2;
#pragma unroll
    for (int j = 0; j < 4; ++j) {
        size_t node = (size_t)tile * 16 + row0 + j;
        qkbuf[node * 48 + 0 + col]  = acc0[j];
        qkbuf[node * 48 + 16 + col] = acc1[j];
        qkbuf[node * 48 + 32 + col] = acc2[j];
    }
}

// ================= single-pass softmax + gather + elu + residual + stats =================
__global__ __launch_bounds__(256) void gather_fused(
    const int* __restrict__ rps, const int* __restrict__ deg, const int* __restrict__ elist,
    const float* __restrict__ qkbuf, const unsigned short* __restrict__ xt,
    const unsigned short* __restrict__ hbin, const float* __restrict__ rb, const int* __restrict__ batch,
    float* __restrict__ gs1, float* __restrict__ gs2, unsigned short* __restrict__ ybuf)
{
    int node = blockIdx.x * 4 + (threadIdx.x >> 6);
    int lane = threadIdx.x & 63;
    bool act = lane < 48;
    int d = deg[node], rp = rps[node];
    int head = lane / 6; if (head > 7) head = 7;
    float qd0 = qkbuf[(size_t)node * 48 + 0 + head];
    float qd1 = qkbuf[(size_t)node * 48 + 16 + head];
    float qd2 = qkbuf[(size_t)node * 48 + 32 + head];
    uint4 hu = {0, 0, 0, 0};
    if (act) hu = *((const uint4*)(hbin + (size_t)node * FF) + lane);
    float s = 0.f;
    float a0 = 0.f, a1 = 0.f, a2 = 0.f, a3 = 0.f, a4 = 0.f, a5 = 0.f, a6 = 0.f, a7 = 0.f;
    for (int base = 0; base < d; base += 64) {
        int myp = (base + lane < d) ? elist[rp + base + lane] : 0;
        int lim = d - base; if (lim > 64) lim = 64;
        for (int e = 0; e < lim; ++e) {
            int packed = __shfl(myp, e);
            int et = packed >> 16, src = packed & 0xFFFF;
            uint4 u = {0, 0, 0, 0};
            if (act) u = *((const uint4*)(xt + ((size_t)et * NN + src) * FF) + lane);
            float qd = et == 0 ? qd0 : (et == 1 ? qd1 : qd2);
            float a = qd + qkbuf[(size_t)src * 48 + et * 16 + 8 + head];
            a = a >= 0.f ? a : NEG_SLOPE * a;
            float pw = __expf(a);
            s += pw;
            a0 = fmaf(pw, bflo(u.x), a0); a1 = fmaf(pw, bfhi(u.x), a1);
            a2 = fmaf(pw, bflo(u.y), a2); a3 = fmaf(pw, bfhi(u.y), a3);
            a4 = fmaf(pw, bflo(u.z), a4); a5 = fmaf(pw, bfhi(u.z), a5);
            a6 = fmaf(pw, bflo(u.w), a6); a7 = fmaf(pw, bfhi(u.w), a7);
        }
    }
    float inv = 1.f / (s + 1e-16f);
    float hv[8] = {bflo(hu.x), bfhi(hu.x), bflo(hu.y), bfhi(hu.y),
                   bflo(hu.z), bfhi(hu.z), bflo(hu.w), bfhi(hu.w)};
    float av[8] = {a0, a1, a2, a3, a4, a5, a6, a7};
    int f0 = lane * 8;
    float s1 = 0.f, s2 = 0.f;
    if (act) {
        float yv[8];
#pragma unroll
        for (int i = 0; i < 8; ++i) {
            float mv = av[i] * inv + rb[f0 + i];
            float e = mv > 0.f ? mv : (__expf(mv) - 1.f);
            float y = hv[i] + e;
            yv[i] = y;
            s1 += y; s2 += y * y;
        }
        uint4 pkv;
        pkv.x = pk2(yv[0], yv[1]); pkv.y = pk2(yv[2], yv[3]);
        pkv.z = pk2(yv[4], yv[5]); pkv.w = pk2(yv[6], yv[7]);
        *((uint4*)(ybuf + (size_t)node * FF) + lane) = pkv;
    }
    s1 = wave_sum(s1);
    s2 = wave_sum(s2);
    if (lane == 0) {
        int g = batch[node];
        atomicAdd(&gs1[g], s1);
        atomicAdd(&gs2[g], s2);
    }
}

// ================= LN apply with inline per-graph finalize (48-lane uint4) =================
__global__ __launch_bounds__(256) void ln_apply(
    const unsigned short* __restrict__ y, const int* __restrict__ batch,
    const float* __restrict__ gcnt, const float* __restrict__ gs1, const float* __restrict__ gs2,
    const float* __restrict__ w, const float* __restrict__ b,
    unsigned short* __restrict__ hbOut)
{
    int n = blockIdx.x * 4 + (threadIdx.x >> 6);
    int lane = threadIdx.x & 63;
    if (lane >= 48 || n >= NN) return;
    int f0 = lane * 8;
    int g = batch[n];
    float cnt = fmaxf(gcnt[g], 1.f) * (float)FF;
    float mean = gs1[g] / cnt;
    float var = fmaxf(gs2[g] / cnt - mean * mean, 0.f);
    float rs = 1.f / sqrtf(var + 1e-5f);
    uint4 u = *((const uint4*)(y + (size_t)n * FF) + lane);
    float yv[8] = {bflo(u.x), bfhi(u.x), bflo(u.y), bfhi(u.y),
                   bflo(u.z), bfhi(u.z), bflo(u.w), bfhi(u.w)};
    float ov[8];
#pragma unroll
    for (int i = 0; i < 8; ++i)
        ov[i] = (yv[i] - mean) * rs * w[f0 + i] + b[f0 + i];
    uint4 pkv;
    pkv.x = pk2(ov[0], ov[1]); pkv.y = pk2(ov[2], ov[3]);
    pkv.z = pk2(ov[4], ov[5]); pkv.w = pk2(ov[6], ov[7]);
    *((uint4*)(hbOut + (size_t)n * FF) + lane) = pkv;
}

// ================= host-side layer driver =================
static void rgat_layer(hipStream_t stream,
    const unsigned short* hbIn,
    const float* rb, const float* lnw, const float* lnb,
    const int* rps, const int* deg, const int* elist, const int* batch,
    const unsigned short* wt, unsigned short* xt, const unsigned short* wqkt, float* qkbuf,
    float* gs, const float* gcnt,
    unsigned short* ybuf, unsigned short* hbOut)
{
    gemm_mfma<0, true, true><<<dim3(384, 3, 3), 256, 0, stream>>>(
        hbIn, FF, wt, nullptr, xt, FF, (size_t)FF * FF, (size_t)NN * FF);
    qk48_mfma<<<NN / 64, 256, 0, stream>>>(hbIn, wqkt, qkbuf);
    gather_fused<<<NN / 4, 256, 0, stream>>>(rps, deg, elist, qkbuf, xt, hbIn, rb, batch,
                                             gs, gs + GG, ybuf);
    ln_apply<<<NN / 4, 256, 0, stream>>>(ybuf, batch, gcnt, gs, gs + GG, lnw, lnb, hbOut);
}

extern "C" void kernel_launch(void* const* d_in, const int* in_sizes, int n_in,
                              void* d_out, int out_size, void* d_ws, size_t ws_size,
                              hipStream_t stream)
{
    const float* x_visual = (const float*)d_in[0];
    const float* x_geom   = (const float*)d_in[1];
    const float* x_prior  = (const float*)d_in[2];
    const float* vis_w  = (const float*)d_in[3];
    const float* vis_b  = (const float*)d_in[4];
    const float* vis_lw = (const float*)d_in[5];
    const float* vis_lb = (const float*)d_in[6];
    const float* geom_w  = (const float*)d_in[7];
    const float* geom_b  = (const float*)d_in[8];
    const float* geom_lw = (const float*)d_in[9];
    const float* geom_lb = (const float*)d_in[10];
    const float* prior_w  = (const float*)d_in[11];
    const float* prior_b  = (const float*)d_in[12];
    const float* prior_lw = (const float*)d_in[13];
    const float* prior_lb = (const float*)d_in[14];
    const float* r1_w = (const float*)d_in[15];
    const float* r1_q = (const float*)d_in[16];
    const float* r1_k = (const float*)d_in[17];
    const float* r1_b = (const float*)d_in[18];
    const float* n1_w = (const float*)d_in[19];
    const float* n1_b = (const float*)d_in[20];
    const float* r2_w = (const float*)d_in[21];
    const float* r2_q = (const float*)d_in[22];
    const float* r2_k = (const float*)d_in[23];
    const float* r2_b = (const float*)d_in[24];
    const float* n2_w = (const float*)d_in[25];
    const float* n2_b = (const float*)d_in[26];
    const float* c_w1 = (const float*)d_in[27];
    const float* c_b1 = (const float*)d_in[28];
    const float* c_w2 = (const float*)d_in[29];
    const float* c_b2 = (const float*)d_in[30];
    const int* ei_o  = (const int*)d_in[31];
    const int* ei_a  = (const int*)d_in[32];
    const int* ei_s  = (const int*)d_in[33];
    const int* batch = (const int*)d_in[34];
    float* out = (float*)d_out;

    char* p = (char*)d_ws;
    auto alloc = [&](size_t bytes) { char* r = p; p += (bytes + 255) & ~(size_t)255; return r; };
    unsigned short* hbA = (unsigned short*)alloc((size_t)NN * FF * 2);
    unsigned short* hbB = (unsigned short*)alloc((size_t)NN * FF * 2);
    unsigned short* ybuf = (unsigned short*)alloc((size_t)NN * FF * 2);
    unsigned short* xt = (unsigned short*)alloc((size_t)3 * NN * FF * 2);
    unsigned short* wt1 = (unsigned short*)alloc((size_t)3 * FF * FF * 2);
    unsigned short* wt2 = (unsigned short*)alloc((size_t)3 * FF * FF * 2);
    unsigned short* wtv = (unsigned short*)alloc((size_t)1024 * 128 * 2);
    unsigned short* wtc = (unsigned short*)alloc((size_t)FF * 128 * 2);
    float* qkbuf = (float*)alloc((size_t)NN * 48 * 4);
    unsigned short* wqkt1 = (unsigned short*)alloc((size_t)48 * FF * 2);
    unsigned short* wqkt2 = (unsigned short*)alloc((size_t)48 * FF * 2);
    float* t128 = (float*)alloc((size_t)NN * 128 * 4);
    int* rps = (int*)alloc(NN * 4);
    int* elist = (int*)alloc(ETOT * 4);
    float* est = (float*)alloc(64);
    float* pbuf = (float*)alloc(ERB * 6 * 4);
    // ---- contiguous zero-init region (one memset) ----
    char* z0 = alloc((size_t)2 * NN * 4 + 256 + (size_t)4 * GG * 4 + GG * 4);
    int* deg = (int*)z0;
    int* fill = deg + NN;
    int* counter = (int*)(z0 + (size_t)2 * NN * 4);
    float* gs = (float*)(z0 + (size_t)2 * NN * 4 + 256);
    float* gcnt = gs + 4 * GG;
    hipMemsetAsync(z0, 0, (size_t)2 * NN * 4 + 256 + (size_t)4 * GG * 4 + GG * 4, stream);

    // ---- CSR build + per-graph node counts ----
    csr_count<<<ETOT / 256, 256, 0, stream>>>(ei_o, ei_a, ei_s, deg);
    csr_alloc<<<NN / 256, 256, 0, stream>>>(deg, counter, rps, batch, gcnt);
    csr_fill<<<ETOT / 256, 256, 0, stream>>>(ei_o, ei_a, ei_s, rps, fill, elist);

    // ---- all weight prep up front ----
    transpose2_bf<<<(6 * FF * FF + 255) / 256, 256, 0, stream>>>(r1_w, r2_w, wt1, wt2);
    wqk_prep2<<<dim3(3, 6, 2), 256, 0, stream>>>(r1_w, r1_q, r1_k, r2_w, r2_q, r2_k, wqkt1, wqkt2);
    transpose_bf<<<(1024 * 128 + 255) / 256, 256, 0, stream>>>(vis_w, wtv, 1024, 128, 1024 * 128);
    transpose_bf<<<(FF * 128 + 255) / 256, 256, 0, stream>>>(c_w1, wtc, FF, 128, FF * 128);

    // ---- encoders (all-bf16 h) ----
    gemm_mfma<1, false, true><<<dim3(384, 1, 1), 256, 0, stream>>>(
        x_visual, 1024, wtv, vis_b, hbA, FF, 0, 0);
    gemm_k2_enc<<<dim3(2, 768, 2), 256, 0, stream>>>(
        x_geom, geom_w, geom_b, x_prior, prior_w, prior_b, hbA);
    enc_reduce_stage1<<<ERB, 256, 0, stream>>>(hbA, pbuf);
    enc_reduce_stage2<<<1, 64, 0, stream>>>(pbuf, est);
    enc_apply<<<NN / 4, 256, 0, stream>>>(
        hbA, est, vis_lw, vis_lb, geom_lw, geom_lb, prior_lw, prior_lb);

    // ---- RGAT layers (bf16 ping-pong hbA -> hbB -> hbA) ----
    rgat_layer(stream, hbA, r1_b, n1_w, n1_b, rps, deg, elist, batch,
               wt1, xt, wqkt1, qkbuf, gs, gcnt, ybuf, hbB);
    rgat_layer(stream, hbB, r2_b, n2_w, n2_b, rps, deg, elist, batch,
               wt2, xt, wqkt2, qkbuf, gs + 2 * GG, gcnt, ybuf, hbA);

    // ---- classifier ----
    gemm_mfma<1, true, false><<<dim3(384, 1, 1), 256, 0, stream>>>(
        hbA, FF, wtc, c_b1, t128, 128, 0, 0);
    gemm_k<0, false><<<dim3(1, 768, 1), 256, 0, stream>>>(t128, 128, c_w2, 49, c_b2, out, 49, 49);
}